// Round 1
// baseline (1492.423 us; speedup 1.0000x reference)
//
#include <hip/hip_runtime.h>

// ---------------------------------------------------------------------------
// Coordinator: 8 agents, bidirectional GRU over ragged-packed sequences.
// I/O fp32. Internal compute: fp16 MFMA (fp32 accumulate), h kept fp32.
// R6: persistent single-launch GRU (k_gru). The recurrence is row-independent,
//     so each block owns (chain, 64 batch rows) for ALL 16 timesteps:
//       - h fp32 in registers, fp16 copy in LDS (A operand). No h/hh global
//         round-trips, no k_init_h / k_hout, no 16 launch overheads.
//       - weights read as MFMA B-frags directly L2->VGPR (wave-private slices,
//         XCD-pinned via ch = bx&15), no LDS staging, no K-loop barriers.
//       - next-step x tile prefetched via global_load_lds under the epilogue.
// ---------------------------------------------------------------------------

typedef _Float16 f16;
typedef __attribute__((ext_vector_type(4))) _Float16 f16x4;
typedef __attribute__((ext_vector_type(8))) _Float16 f16x8;
typedef __attribute__((ext_vector_type(4))) float floatx4;

__device__ __forceinline__ float sigf(float x) { return 1.0f / (1.0f + __expf(-x)); }
__device__ __forceinline__ float tanhfast(float x) {
    float e = __expf(2.0f * x);
    return 1.0f - 2.0f / (e + 1.0f);   // saturates correctly, no NaN at +/-inf
}

// async global->LDS, 16B per lane; lds dst = wave-uniform base + lane*16
__device__ __forceinline__ void gl16(const f16* g, f16* l) {
    __builtin_amdgcn_global_load_lds((const __attribute__((address_space(1))) void*)g,
                                     (__attribute__((address_space(3))) void*)l,
                                     16, 0, 0);
}

// ---------------- empty[b] = no nonzero in comm_plans[b,:,:] -----------------
__global__ void k_empty(const float* __restrict__ comm, int* __restrict__ empty) {
    int b = blockIdx.x;
    __shared__ int flag;
    if (threadIdx.x == 0) flag = 0;
    __syncthreads();
    const float* p = comm + (size_t)b * 1024;   // 8*128
    int any = 0;
    for (int e = threadIdx.x; e < 1024; e += 256)
        if (p[e] != 0.0f) any = 1;              // -0.0 compares equal to 0
    if (any) flag = 1;
    __syncthreads();
    if (threadIdx.x == 0) empty[b] = (flag == 0);
}

// ---------------- mask[t*1024+b]: t>=8 -> 1 ; t<8 -> any(comm_sel != 0) ------
__global__ void k_mask(const float* __restrict__ plans, const float* __restrict__ comm,
                       const int* __restrict__ empty, int* __restrict__ mask) {
    int row = blockIdx.x * 4 + (threadIdx.x >> 6);   // one wave per (t,b) row
    int lane = threadIdx.x & 63;
    int t = row >> 10, b = row & 1023;
    int m;
    if (t >= 8) {
        m = 1;
    } else {
        const float* src = (empty[b] ? plans : comm) + ((size_t)b * 8 + t) * 128;
        float v0 = src[lane * 2], v1 = src[lane * 2 + 1];
        m = __any((v0 != 0.0f) || (v1 != 0.0f)) ? 1 : 0;
    }
    if (lane == 0) mask[row] = m;
}

// ---------------- single-block scan: seq_len, pack_src, scat_src, inv_scat ---
// Reproduces torch flat row-major boolean-index / masked_scatter semantics.
__global__ void k_scan(const int* __restrict__ mask, int* __restrict__ seq_len,
                       int* __restrict__ pack_src, int* __restrict__ scat_src,
                       int* __restrict__ inv_scat) {
    __shared__ int s_sl[1024];
    __shared__ int s_m[1024];
    __shared__ int s_p[1024];
    __shared__ unsigned short s_idx[16384];  // src_idx (j fits in 16 bits)
    int tid = threadIdx.x;
    int sl = 8;
    for (int t = 0; t < 8; t++) sl += mask[t * 1024 + tid];
    s_sl[tid] = sl;
    seq_len[tid] = sl;
    __syncthreads();
    int mv[16], pv[16];
    int mc = 0, pc = 0;
    int j0 = tid * 16;
    for (int q = 0; q < 16; q++) {
        int j = j0 + q;
        mv[q] = mask[j];
        pv[q] = ((j >> 10) < s_sl[j & 1023]) ? 1 : 0;
        mc += mv[q]; pc += pv[q];
    }
    s_m[tid] = mc; s_p[tid] = pc;
    __syncthreads();
    for (int off = 1; off < 1024; off <<= 1) {   // Hillis-Steele inclusive scan
        int am = (tid >= off) ? s_m[tid - off] : 0;
        int ap = (tid >= off) ? s_p[tid - off] : 0;
        __syncthreads();
        s_m[tid] += am; s_p[tid] += ap;
        __syncthreads();
    }
    if (tid == 1023) seq_len[1024] = s_m[1023];  // T = total masked count
    int moff = s_m[tid] - mc;    // exclusive prefixes
    int poff = s_p[tid] - pc;
    int rm = moff;
    for (int q = 0; q < 16; q++)
        if (mv[q]) s_idx[rm++] = (unsigned short)(j0 + q);
    __syncthreads();
    rm = moff;
    int rp = poff;
    for (int q = 0; q < 16; q++) {
        int j = j0 + q;
        scat_src[j] = mv[q] ? rm : -1;
        if (mv[q]) { inv_scat[rm] = j; rm++; }
        pack_src[j] = pv[q] ? (int)s_idx[rp] : -1;
        if (pv[q]) rp++;
    }
}

// ---------------- gather packed sequences: cseq[i][t][b][c] (fp16) -----------
// block = 8 rows x 32 lanes; lane covers 8 contiguous cols (2x float4 load).
__global__ void k_pack(const float* __restrict__ plans, const float* __restrict__ comm,
                       const float* __restrict__ dummy, const int* __restrict__ empty,
                       const int* __restrict__ pack_src, f16* __restrict__ cseq) {
    int row = blockIdx.x * 8 + (threadIdx.x >> 5);   // i*16384 + j
    int lane = threadIdx.x & 31;
    int i = row >> 14;
    int j = row & 16383;
    int s = pack_src[j];
    f16x8 o = {0, 0, 0, 0, 0, 0, 0, 0};
    if (s >= 0) {
        int tp = s >> 10, bp = s & 1023;
        const float* src;
        if (tp < 8) {
            if (lane < 16) src = plans + ((size_t)bp * 8 + i) * 128 + lane * 8;
            else src = (empty[bp] ? plans : comm) + ((size_t)bp * 8 + tp) * 128 + (lane - 16) * 8;
        } else {
            src = dummy + (((size_t)i * 8 + (tp - 8)) * 1024 + bp) * 256 + lane * 8;
        }
        float4 v0 = *(const float4*)src;
        float4 v1 = *(const float4*)(src + 4);
        o[0] = (f16)v0.x; o[1] = (f16)v0.y; o[2] = (f16)v0.z; o[3] = (f16)v0.w;
        o[4] = (f16)v1.x; o[5] = (f16)v1.y; o[6] = (f16)v1.z; o[7] = (f16)v1.w;
    }
    *(f16x8*)(cseq + ((size_t)row << 8) + lane * 8) = o;
}

// ---------------- weight pre-convert fp32 -> fp16 ----------------------------
// whalf layout: [ch=2i+d][sel: 0=Wi,1=Wh][row 768][k 256]
__global__ void k_prep_w(const float* __restrict__ Wi_f, const float* __restrict__ Wh_f,
                         const float* __restrict__ Wi_b, const float* __restrict__ Wh_b,
                         f16* __restrict__ whalf) {
    int ch2 = blockIdx.y;                // ch*2 + sel
    int ch = ch2 >> 1, sel = ch2 & 1;
    int i = ch >> 1, d = ch & 1;
    const float* src = sel ? (d ? Wh_b : Wh_f) : (d ? Wi_b : Wi_f);
    src += (size_t)i * 196608;
    int off = (blockIdx.x * 256 + threadIdx.x) * 4;
    float4 v = *(const float4*)(src + off);
    f16x4 o = { (f16)v.x, (f16)v.y, (f16)v.z, (f16)v.w };
    *(f16x4*)(whalf + (size_t)ch2 * 196608 + off) = o;
}

__global__ void k_prep_w1(const float* __restrict__ W1, f16* __restrict__ w1half) {
    int off = (blockIdx.x * 256 + threadIdx.x) * 4;
    float4 v = *(const float4*)(W1 + off);
    f16x4 o = { (f16)v.x, (f16)v.y, (f16)v.z, (f16)v.w };
    *(f16x4*)(w1half + off) = o;
}

// ---------------- zero-fill scores rows/halves never written by steps --------
__global__ void k_zfill(const int* __restrict__ scat_src, const int* __restrict__ seq_len,
                        f16* __restrict__ scores) {
    int j = blockIdx.x;
    int tid = threadIdx.x;
    int c = scat_src[j];
    if (c < 0) {                          // unmasked row: all 512 cols zero
        for (int i = 0; i < 8; i++) {
            unsigned int* p = (unsigned int*)(scores + ((size_t)(i * 16384 + j)) * 512);
            p[tid] = 0u;                  // 256 threads x 2 halfs = 512
        }
    } else {                              // masked row fed from past-end source: bwd half zero
        int st = c >> 10, sb = c & 1023;
        if (st >= seq_len[sb] && tid < 128) {
            for (int i = 0; i < 8; i++) {
                unsigned int* p = (unsigned int*)(scores + ((size_t)(i * 16384 + j)) * 512 + 256);
                p[tid] = 0u;
            }
        }
    }
}

// ---------------- persistent fused GRU: all 16 timesteps in one launch -------
// grid 256 = 16 ch (bx&15, XCD-pinned) x 16 row-tiles of 64; 512 threads.
// Wave w owns gate-cols [w*32, w*32+32) of all 3 gates; B-frags L2->reg.
// LDS: lX (x tile, swizzled) + lH (h fp16, swizzled); h fp32 in registers.
__global__ __launch_bounds__(512, 2) void k_gru(
    const f16* __restrict__ cseq, const f16* __restrict__ whalf,
    const float* __restrict__ hx, f16* __restrict__ scores,
    const int* __restrict__ seq_len, const int* __restrict__ inv_scat,
    float* __restrict__ out)
{
    __shared__ f16 lX[64 * 256];          // 32 KB, chunk-XOR swizzled
    __shared__ f16 lH[64 * 256];          // 32 KB, chunk-XOR swizzled
    const int bx = blockIdx.x;
    const int ch = bx & 15;               // chain -> XCD ch%8 (weights L2-local)
    const int mt = bx >> 4;               // rows mt*64 .. mt*64+63
    const int i = ch >> 1, d = ch & 1;
    const int tid = threadIdx.x;
    const int lane = tid & 63, w = tid >> 6;
    const int li = lane & 15, q = lane >> 4;
    const int x7 = li & 7;

    // ---- staging geometry: wave w stages lX rows w*8..w*8+7 (gl16) ----
    int bst[4], scp[4], slst[4];
    {
        int sub2 = lane >> 5;             // 0/1: which of the 2 rows per gl16
        int ss = lane & 31;               // 16B-sliver position within row
        int sg = ss >> 3, sb = ss & 7;
#pragma unroll
        for (int p = 0; p < 4; p++) {
            int r8 = 2 * p + sub2;                    // row within wave's 8 == row&7
            bst[p] = mt * 64 + w * 8 + r8;
            scp[p] = (sg * 8 + (sb ^ r8)) * 8;        // pre-swizzled src offset (halves)
            slst[p] = seq_len[bst[p]];
        }
    }
    const int T = seq_len[1024];

    // ---- per-thread output geometry, h init (fp32 regs + fp16 LDS) ----
    // acc element (m,n,r): b = mt*64 + m*16 + q*4 + r ; c = w*32 + n*16 + li
    int slmr[4][4];
    float hreg[4][2][4];
#pragma unroll
    for (int m = 0; m < 4; m++)
#pragma unroll
        for (int r = 0; r < 4; r++) {
            int b = mt * 64 + m * 16 + q * 4 + r;
            slmr[m][r] = seq_len[b];
            int row = m * 16 + q * 4 + r;
#pragma unroll
            for (int n = 0; n < 2; n++) {
                int c = w * 32 + n * 16 + li;
                float v = hx[((size_t)ch * 1024 + b) * 256 + c];
                hreg[m][n][r] = v;
                lH[row * 256 + (c >> 6) * 64 + ((((c >> 3) & 7) ^ (row & 7)) << 3) + (c & 7)] = (f16)v;
            }
        }

    // ---- weight B-frag base: frag row = g*256 + w*32 + n*16 + li, k = kk*32+q*8
    const f16* wb = whalf + (size_t)(ch * 2) * 196608 + (size_t)li * 256 + q * 8;
    int O[3][2];
#pragma unroll
    for (int g = 0; g < 3; g++)
#pragma unroll
        for (int n = 0; n < 2; n++)
            O[g][n] = (g * 256 + w * 32 + n * 16) * 256;

    // ---- stage x tile for t=0 ----
#pragma unroll
    for (int p = 0; p < 4; p++) {
        int tt = d ? (slst[p] - 1) : 0;                // sl >= 8, no clamp needed at t=0
        gl16(cseq + (((size_t)i * 16 + tt) * 1024 + bst[p]) * 256 + scp[p],
             &lX[(w * 8 + 2 * p) * 256]);
    }

    floatx4 accr[4][2], accz[4][2], accgi[4][2], accgh[4][2];
    const floatx4 z4 = {0.f, 0.f, 0.f, 0.f};

#pragma unroll 1
    for (int t = 0; t < 16; t++) {
#pragma unroll
        for (int m = 0; m < 4; m++)
#pragma unroll
            for (int n = 0; n < 2; n++) {
                accr[m][n] = z4; accz[m][n] = z4; accgi[m][n] = z4; accgh[m][n] = z4;
            }
        __syncthreads();                  // lX(t) staged, lH(t) written

        // x phase: K=0..255 from lX, Wi (sel=0); r,z,gi
#pragma unroll
        for (int kk = 0; kk < 8; kk++) {
            int sw = (kk >> 1) * 64 + ((((kk & 1) * 4 + q) ^ x7) << 3);
            f16x8 a0 = *(const f16x8*)&lX[(0 * 16 + li) * 256 + sw];
            f16x8 a1 = *(const f16x8*)&lX[(1 * 16 + li) * 256 + sw];
            f16x8 a2 = *(const f16x8*)&lX[(2 * 16 + li) * 256 + sw];
            f16x8 a3 = *(const f16x8*)&lX[(3 * 16 + li) * 256 + sw];
#pragma unroll
            for (int n = 0; n < 2; n++) {
                f16x8 br = *(const f16x8*)(wb + O[0][n] + kk * 32);
                f16x8 bz = *(const f16x8*)(wb + O[1][n] + kk * 32);
                f16x8 bn = *(const f16x8*)(wb + O[2][n] + kk * 32);
                accr[0][n] = __builtin_amdgcn_mfma_f32_16x16x32_f16(a0, br, accr[0][n], 0, 0, 0);
                accr[1][n] = __builtin_amdgcn_mfma_f32_16x16x32_f16(a1, br, accr[1][n], 0, 0, 0);
                accr[2][n] = __builtin_amdgcn_mfma_f32_16x16x32_f16(a2, br, accr[2][n], 0, 0, 0);
                accr[3][n] = __builtin_amdgcn_mfma_f32_16x16x32_f16(a3, br, accr[3][n], 0, 0, 0);
                accz[0][n] = __builtin_amdgcn_mfma_f32_16x16x32_f16(a0, bz, accz[0][n], 0, 0, 0);
                accz[1][n] = __builtin_amdgcn_mfma_f32_16x16x32_f16(a1, bz, accz[1][n], 0, 0, 0);
                accz[2][n] = __builtin_amdgcn_mfma_f32_16x16x32_f16(a2, bz, accz[2][n], 0, 0, 0);
                accz[3][n] = __builtin_amdgcn_mfma_f32_16x16x32_f16(a3, bz, accz[3][n], 0, 0, 0);
                accgi[0][n] = __builtin_amdgcn_mfma_f32_16x16x32_f16(a0, bn, accgi[0][n], 0, 0, 0);
                accgi[1][n] = __builtin_amdgcn_mfma_f32_16x16x32_f16(a1, bn, accgi[1][n], 0, 0, 0);
                accgi[2][n] = __builtin_amdgcn_mfma_f32_16x16x32_f16(a2, bn, accgi[2][n], 0, 0, 0);
                accgi[3][n] = __builtin_amdgcn_mfma_f32_16x16x32_f16(a3, bn, accgi[3][n], 0, 0, 0);
            }
        }
        // h phase: K from lH, Wh (sel=1); r,z,gh
#pragma unroll
        for (int kk = 0; kk < 8; kk++) {
            int sw = (kk >> 1) * 64 + ((((kk & 1) * 4 + q) ^ x7) << 3);
            f16x8 a0 = *(const f16x8*)&lH[(0 * 16 + li) * 256 + sw];
            f16x8 a1 = *(const f16x8*)&lH[(1 * 16 + li) * 256 + sw];
            f16x8 a2 = *(const f16x8*)&lH[(2 * 16 + li) * 256 + sw];
            f16x8 a3 = *(const f16x8*)&lH[(3 * 16 + li) * 256 + sw];
#pragma unroll
            for (int n = 0; n < 2; n++) {
                f16x8 br = *(const f16x8*)(wb + 196608 + O[0][n] + kk * 32);
                f16x8 bz = *(const f16x8*)(wb + 196608 + O[1][n] + kk * 32);
                f16x8 bn = *(const f16x8*)(wb + 196608 + O[2][n] + kk * 32);
                accr[0][n] = __builtin_amdgcn_mfma_f32_16x16x32_f16(a0, br, accr[0][n], 0, 0, 0);
                accr[1][n] = __builtin_amdgcn_mfma_f32_16x16x32_f16(a1, br, accr[1][n], 0, 0, 0);
                accr[2][n] = __builtin_amdgcn_mfma_f32_16x16x32_f16(a2, br, accr[2][n], 0, 0, 0);
                accr[3][n] = __builtin_amdgcn_mfma_f32_16x16x32_f16(a3, br, accr[3][n], 0, 0, 0);
                accz[0][n] = __builtin_amdgcn_mfma_f32_16x16x32_f16(a0, bz, accz[0][n], 0, 0, 0);
                accz[1][n] = __builtin_amdgcn_mfma_f32_16x16x32_f16(a1, bz, accz[1][n], 0, 0, 0);
                accz[2][n] = __builtin_amdgcn_mfma_f32_16x16x32_f16(a2, bz, accz[2][n], 0, 0, 0);
                accz[3][n] = __builtin_amdgcn_mfma_f32_16x16x32_f16(a3, bz, accz[3][n], 0, 0, 0);
                accgh[0][n] = __builtin_amdgcn_mfma_f32_16x16x32_f16(a0, bn, accgh[0][n], 0, 0, 0);
                accgh[1][n] = __builtin_amdgcn_mfma_f32_16x16x32_f16(a1, bn, accgh[1][n], 0, 0, 0);
                accgh[2][n] = __builtin_amdgcn_mfma_f32_16x16x32_f16(a2, bn, accgh[2][n], 0, 0, 0);
                accgh[3][n] = __builtin_amdgcn_mfma_f32_16x16x32_f16(a3, bn, accgh[3][n], 0, 0, 0);
            }
        }
        __syncthreads();                  // all lX/lH reads of step t done

        // prefetch next x tile (drains at next top-of-loop barrier)
        if (t < 15) {
#pragma unroll
            for (int p = 0; p < 4; p++) {
                int tt = t + 1;
                if (d) { tt = slst[p] - 2 - t; if (tt < 0) tt = 0; }  // = sl-1-(t+1), clamped
                gl16(cseq + (((size_t)i * 16 + tt) * 1024 + bst[p]) * 256 + scp[p],
                     &lX[(w * 8 + 2 * p) * 256]);
            }
        }

        // epilogue: gates + h update (regs) + lH(t+1) + masked_scatter scores
#pragma unroll
        for (int m = 0; m < 4; m++)
#pragma unroll
            for (int r = 0; r < 4; r++) {
                int b = mt * 64 + m * 16 + q * 4 + r;
                int sl = slmr[m][r];
                int v = (t < sl);
                int st = d ? (sl - 1 - t) : t;
                int cfl = st * 1024 + b;
                int j = -1;
                if (d == 0) { if (cfl < T) j = inv_scat[cfl]; }
                else        { if (v && cfl < T) j = inv_scat[cfl]; }
                int row = m * 16 + q * 4 + r;
#pragma unroll
                for (int n = 0; n < 2; n++) {
                    int c = w * 32 + n * 16 + li;
                    float rg = sigf(accr[m][n][r]);
                    float zg = sigf(accz[m][n][r]);
                    float nn = tanhfast(accgi[m][n][r] + rg * accgh[m][n][r]);
                    float hp = hreg[m][n][r];
                    float hn = (1.0f - zg) * nn + zg * hp;
                    float hnew = v ? hn : hp;
                    hreg[m][n][r] = hnew;
                    lH[row * 256 + (c >> 6) * 64 + ((((c >> 3) & 7) ^ (row & 7)) << 3) + (c & 7)] = (f16)hnew;
                    if (j >= 0)
                        scores[((size_t)(i * 16384 + j)) * 512 + d * 256 + c] = (f16)(v ? hn : 0.0f);
                    if (t == 15)
                        out[262144 + ((size_t)ch * 1024 + b) * 256 + c] = hnew;
                }
            }
    }
}

// ---------------- fused LN(stats+apply) + MLP -> coord_masks -----------------
// grid: i(8) x mt(128, M=128); 512 threads (8 waves). N=256, K=512.
__global__ __launch_bounds__(512, 4) void k_mlp(
    const f16* __restrict__ scores,
    const float* __restrict__ ln_g, const float* __restrict__ ln_b,
    const f16* __restrict__ w1half, const float* __restrict__ b1,
    const float* __restrict__ W2, const float* __restrict__ b2,
    float* __restrict__ out)
{
    __shared__ f16 lA[128 * 64];          // 16 KB
    __shared__ f16 lB[256 * 64];          // 32 KB
    __shared__ float s_mu[128], s_rs[128];
    int bx = blockIdx.x;
    int i = bx >> 7, mt = bx & 127;
    int tid = threadIdx.x, lane = tid & 63, w = tid >> 6, li = lane & 15, q = lane >> 4;
    int rsub = lane >> 3;
    int sc = (lane & 7) ^ rsub;

    // ---- stats pre-pass: 4 threads per row, 128 cols each ----
    {
        int r = tid >> 2, sub = tid & 3;
        const f16* sp = scores + ((size_t)(i * 16384 + mt * 128 + r)) * 512 + sub * 128;
        float s = 0.f, sq = 0.f;
#pragma unroll
        for (int e = 0; e < 16; e++) {
            uint4 raw = *(const uint4*)(sp + e * 8);
            f16x8 v = *(f16x8*)&raw;
#pragma unroll
            for (int u = 0; u < 8; u++) { float f = (float)v[u]; s += f; sq += f * f; }
        }
        s += __shfl_xor(s, 1); sq += __shfl_xor(sq, 1);
        s += __shfl_xor(s, 2); sq += __shfl_xor(sq, 2);
        if (sub == 0) {
            float mu = s * (1.0f / 512.0f);
            float var = sq * (1.0f / 512.0f) - mu * mu;
            if (var < 0.f) var = 0.f;
            s_mu[r] = mu;
            s_rs[r] = rsqrtf(var + 1e-5f);
        }
    }

    // B source pointers (lds-direct)
    const f16* pB[4];
#pragma unroll
    for (int p = 0; p < 4; p++) {
        int nr = (w * 4 + p) * 8 + rsub;                 // 0..255
        pB[p] = w1half + ((size_t)i * 256 + nr) * 512 + sc * 8;
    }

    floatx4 acc[16];
    floatx4 z4 = {0.f, 0.f, 0.f, 0.f};
#pragma unroll
    for (int n = 0; n < 16; n++) acc[n] = z4;
    __syncthreads();   // stats visible

    for (int kt = 0; kt < 512; kt += 64) {
        // A stage (manual, LN applied on load, swizzled store)
#pragma unroll
        for (int p = 0; p < 2; p++) {
            int e = p * 512 + tid;
            int ar = e >> 3, chk = e & 7;
            int m = mt * 128 + ar;
            uint4 raw = *(const uint4*)(scores + ((size_t)(i * 16384 + m)) * 512 + kt + chk * 8);
            f16x8 sv = *(f16x8*)&raw;
            float mu = s_mu[ar], rs = s_rs[ar];
            int co = i * 512 + kt + chk * 8;
            float4 g0 = *(const float4*)(ln_g + co);
            float4 g1 = *(const float4*)(ln_g + co + 4);
            float4 t0 = *(const float4*)(ln_b + co);
            float4 t1 = *(const float4*)(ln_b + co + 4);
            f16x8 ov;
            ov[0] = (f16)(((float)sv[0] - mu) * rs * g0.x + t0.x);
            ov[1] = (f16)(((float)sv[1] - mu) * rs * g0.y + t0.y);
            ov[2] = (f16)(((float)sv[2] - mu) * rs * g0.z + t0.z);
            ov[3] = (f16)(((float)sv[3] - mu) * rs * g0.w + t0.w);
            ov[4] = (f16)(((float)sv[4] - mu) * rs * g1.x + t1.x);
            ov[5] = (f16)(((float)sv[5] - mu) * rs * g1.y + t1.y);
            ov[6] = (f16)(((float)sv[6] - mu) * rs * g1.z + t1.z);
            ov[7] = (f16)(((float)sv[7] - mu) * rs * g1.w + t1.w);
            *(f16x8*)&lA[ar * 64 + ((chk ^ (ar & 7)) << 3)] = ov;
        }
        // B stage: lds-direct
#pragma unroll
        for (int p = 0; p < 4; p++) gl16(pB[p] + kt, &lB[(w * 4 + p) * 512]);
        __syncthreads();
#pragma unroll
        for (int kk = 0; kk < 64; kk += 32) {
            int sw = ((q + (kk >> 3)) ^ (li & 7)) << 3;
            f16x8 a = *(f16x8*)&lA[(w * 16 + li) * 64 + sw];
#pragma unroll
            for (int n = 0; n < 16; n++) {
                f16x8 bb = *(f16x8*)&lB[(n * 16 + li) * 64 + sw];
                acc[n] = __builtin_amdgcn_mfma_f32_16x16x32_f16(a, bb, acc[n], 0, 0, 0);
            }
        }
        __syncthreads();
    }

    // epilogue: relu + W2 dot, reduce over 16 lanes of the quad-row
    float b1v[16], w2a[16], w2b[16];
#pragma unroll
    for (int n = 0; n < 16; n++) {
        int col = n * 16 + li;
        b1v[n] = b1[i * 256 + col];
        w2a[n] = W2[((size_t)i * 2 + 0) * 256 + col];
        w2b[n] = W2[((size_t)i * 2 + 1) * 256 + col];
    }
    float b2a = b2[i * 2], b2b = b2[i * 2 + 1];
#pragma unroll
    for (int r = 0; r < 4; r++) {
        float p0 = 0.f, p1 = 0.f;
#pragma unroll
        for (int n = 0; n < 16; n++) {
            float h1 = acc[n][r] + b1v[n];
            h1 = fmaxf(h1, 0.0f);
            p0 += h1 * w2a[n];
            p1 += h1 * w2b[n];
        }
#pragma unroll
        for (int off = 1; off < 16; off <<= 1) { p0 += __shfl_xor(p0, off); p1 += __shfl_xor(p1, off); }
        if (li == 0) {
            int m = mt * 128 + w * 16 + q * 4 + r;
            size_t oi = ((size_t)i * 16384 + m) * 2;
            out[oi]     = p0 + b2a;
            out[oi + 1] = p1 + b2b;
        }
    }
}

// ---------------------------------------------------------------------------
extern "C" void kernel_launch(void* const* d_in, const int* in_sizes, int n_in,
                              void* d_out, int out_size, void* d_ws, size_t ws_size,
                              hipStream_t stream)
{
    const float* plans = (const float*)d_in[0];
    const float* comm  = (const float*)d_in[1];
    const float* hx    = (const float*)d_in[2];
    const float* dummy = (const float*)d_in[3];
    const float* Wi_f  = (const float*)d_in[4];
    const float* Wh_f  = (const float*)d_in[5];
    const float* Wi_b  = (const float*)d_in[6];
    const float* Wh_b  = (const float*)d_in[7];
    const float* ln_g  = (const float*)d_in[8];
    const float* ln_b  = (const float*)d_in[9];
    const float* W1    = (const float*)d_in[10];
    const float* b1    = (const float*)d_in[11];
    const float* W2    = (const float*)d_in[12];
    const float* b2    = (const float*)d_in[13];
    float* out = (float*)d_out;

    // ws layout (h/hh regions from R5 no longer used)
    char* ws = (char*)d_ws;
    f16*    cseq    = (f16*)   (ws + 0);            //  67,108,864 B
    f16*    scores  = (f16*)   (ws + 67108864);     // 134,217,728 B
    f16*    whalf   = (f16*)   (ws + 234881024);    //  12,582,912 B
    f16*    w1half  = (f16*)   (ws + 247463936);    //   2,097,152 B
    int*    empty   = (int*)   (ws + 250609664);    //       4,096 B
    int*    seq_len = (int*)   (ws + 250613760);    //       8,192 B (1025 used)
    int*    maskb   = (int*)   (ws + 250621952);    //      65,536 B
    int*    pack_s  = (int*)   (ws + 250687488);    //      65,536 B
    int*    scat_s  = (int*)   (ws + 250753024);    //      65,536 B
    int*    inv_s   = (int*)   (ws + 250818560);    //      65,536 B
    if (ws_size < 250884096ULL) return;  // fail readably instead of faulting

    k_empty<<<1024, 256, 0, stream>>>(comm, empty);
    k_mask<<<4096, 256, 0, stream>>>(plans, comm, empty, maskb);
    k_scan<<<1, 1024, 0, stream>>>(maskb, seq_len, pack_s, scat_s, inv_s);
    k_pack<<<16384, 256, 0, stream>>>(plans, comm, dummy, empty, pack_s, cseq);
    k_zfill<<<16384, 256, 0, stream>>>(scat_s, seq_len, scores);
    k_prep_w<<<dim3(192, 32), 256, 0, stream>>>(Wi_f, Wh_f, Wi_b, Wh_b, whalf);
    k_prep_w1<<<1024, 256, 0, stream>>>(W1, w1half);
    k_gru<<<256, 512, 0, stream>>>(cseq, whalf, hx, scores, seq_len, inv_s, out);
    k_mlp<<<1024, 512, 0, stream>>>(scores, ln_g, ln_b, w1half, b1, W2, b2, out);
}